// Round 1
// 912.691 us; speedup vs baseline: 1.4779x; 1.4779x over previous
//
#include <hip/hip_runtime.h>
#include <math.h>

typedef unsigned short u16;
typedef unsigned int u32;
typedef __bf16 bf16;
typedef __attribute__((ext_vector_type(8))) __bf16 bf16x8;
typedef __attribute__((ext_vector_type(4))) float f32x4;

#define NB 16
#define NC 512
#define NL 4096
#define ND 384
#define NW 256      // pooled length n
#define NIN 512     // inner
#define NFF 1536
#define NM (NB*NW)  // 4096 rows
#define ATT_SCALE 0.125f

__device__ __forceinline__ float gelu_f(float x) {
  return 0.5f * x * (1.f + erff(x * 0.70710678118654752f));
}

// ---- fp32 -> bf16 hi/lo split (RNE via bit math; lo = exact residual rounded)
__device__ __forceinline__ u16 bf_hi(float f) {
  u32 u = __float_as_uint(f);
  u32 r = u + 0x7FFFu + ((u >> 16) & 1u);
  return (u16)(r >> 16);
}
__device__ __forceinline__ float bf_f(u16 h) { return __uint_as_float((u32)h << 16); }
__device__ __forceinline__ void split_bf(float f, u16& h, u16& l) {
  h = bf_hi(f);
  l = bf_hi(f - bf_f(h));
}

// ---- pool: x[b][c][0:4096] -> mean over 16 -> split-bf16 planes xpT[(b*256+n)][c]
__global__ __launch_bounds__(256) void pool_kernel(const float* __restrict__ x,
                                                   u16* __restrict__ xh, u16* __restrict__ xl) {
  int blk = blockIdx.x;            // b*512 + c
  int b = blk >> 9, c = blk & 511;
  int t = threadIdx.x;             // window index n
  const float4* p = (const float4*)(x + (size_t)blk * NL) + t * 4;
  float s = 0.f;
#pragma unroll
  for (int i = 0; i < 4; ++i) {
    float4 v = p[i];
    s += v.x + v.y + v.z + v.w;
  }
  u16 hh, ll; split_bf(s * (1.f / 16.f), hh, ll);
  size_t off = ((size_t)b * NW + t) * NC + c;
  xh[off] = hh; xl[off] = ll;
}

// ---- elementwise split (weights already in [N][K] layout)
__global__ __launch_bounds__(256) void split_kernel(const float* __restrict__ src,
                                                    u16* __restrict__ dh, u16* __restrict__ dl, int n) {
  int i = blockIdx.x * 256 + threadIdx.x;
  if (i >= n) return;
  u16 h, l; split_bf(src[i], h, l);
  dh[i] = h; dl[i] = l;
}

// ---- transpose+split: src[R][C] f32 -> dst planes [C][R] bf16 (dst[c][r]=src[r][c])
__global__ __launch_bounds__(256) void tsplit_kernel(const float* __restrict__ src,
                                                     u16* __restrict__ dh, u16* __restrict__ dl,
                                                     int R, int C) {
  __shared__ float tile[32][33];
  const int tc = blockIdx.x * 32, tr = blockIdx.y * 32;
  const int lx = threadIdx.x & 31, ly = threadIdx.x >> 5;   // 32 x 8
#pragma unroll
  for (int p = 0; p < 4; ++p)
    tile[ly + p * 8][lx] = src[(size_t)(tr + ly + p * 8) * C + tc + lx];
  __syncthreads();
#pragma unroll
  for (int p = 0; p < 4; ++p) {
    const int c = tc + ly + p * 8;
    const float v = tile[lx][ly + p * 8];
    u16 h, l; split_bf(v, h, l);
    dh[(size_t)c * R + tr + lx] = h;
    dl[(size_t)c * R + tr + lx] = l;
  }
}

// ---- conv weight: BT[n=dout][k=j*384+dp] = local_w[dout][dp][j], split planes
__global__ __launch_bounds__(256) void convw_split_kernel(const float* __restrict__ lw,
                                                          u16* __restrict__ dh, u16* __restrict__ dl) {
  int idx = blockIdx.x * 256 + threadIdx.x;       // over 384*1152
  if (idx >= 384 * 1152) return;
  int n = idx / 1152, k = idx - n * 1152;
  int j = k / 384, dp = k - j * 384;
  u16 h, l; split_bf(lw[(size_t)n * 1152 + dp * 3 + j], h, l);
  dh[idx] = h; dl[idx] = l;
}

// ---- MFMA split-bf16 GEMM.  C[m][n] = f(A@B^T + bias) (+res)
// A planes: [M][K] bf16 hi/lo.  B planes: [N][K] bf16 hi/lo (pre-transposed weights).
// BM=128 fixed, BN in {64,128}. 256 threads = 4 waves (2x2), wave tile 64 x BN/2.
// LDS tiles [rows][32] bf16, XOR-swizzle byte^=((row&7)<<4) -> <=2-way bank conflicts (free).
// 3-product emulation: acc += Ah*Bh + Al*Bh + Ah*Bl  (drops Al*Bl ~ 2^-18 rel).
template<int BN, bool GELU, bool SPLITOUT>
__global__ __launch_bounds__(256) void mgemm(
    const u16* __restrict__ Ah_g, const u16* __restrict__ Al_g,
    const u16* __restrict__ Bh_g, const u16* __restrict__ Bl_g,
    const float* __restrict__ bias, const float* res,
    float* C, u16* Ch, u16* Cl, int N, int K)
{
  constexpr int FN = BN / 32;
  constexpr int WN = BN / 2;
  __shared__ __align__(16) u16 Ah_s[128 * 32], Al_s[128 * 32];
  __shared__ __align__(16) u16 Bh_s[BN * 32],  Bl_s[BN * 32];

  const int t = threadIdx.x;
  const int bm = blockIdx.y * 128;
  const int bn = blockIdx.x * BN;

  // staging: 16B chunks; A has 512 chunks (2/thread), B has BN*4 chunks
  const int ra0 = t >> 2, ra1 = ra0 + 64;
  const int ca = (t & 3) * 8;
  const size_t ga0 = (size_t)(bm + ra0) * K + ca;
  const size_t ga1 = (size_t)(bm + ra1) * K + ca;
  const int wa0 = (ra0 * 32 + ca) ^ ((ra0 & 7) << 3);
  const int wa1 = (ra1 * 32 + ca) ^ ((ra1 & 7) << 3);
  const size_t gb0 = (size_t)(bn + ra0) * K + ca;
  const int wb0 = wa0;
  size_t gb1 = 0; int wb1 = 0;
  if constexpr (BN == 128) { gb1 = (size_t)(bn + ra1) * K + ca; wb1 = wa1; }

  // fragment offsets (A: row=lane&15, k=(lane>>4)*8+e ; B symmetric on [N][K])
  const int lane = t & 63;
  const int w = t >> 6, wm = w >> 1, wn = w & 1;
  const int lr = lane & 15;
  const int kb = (lane >> 4) << 3;
  int aoff[4], boff[FN];
#pragma unroll
  for (int i = 0; i < 4; ++i) {
    int r = wm * 64 + i * 16 + lr;
    aoff[i] = (r * 32 + kb) ^ ((r & 7) << 3);
  }
#pragma unroll
  for (int j = 0; j < FN; ++j) {
    int r = wn * WN + j * 16 + lr;
    boff[j] = (r * 32 + kb) ^ ((r & 7) << 3);
  }

  f32x4 acc[4][FN];
#pragma unroll
  for (int i = 0; i < 4; ++i)
#pragma unroll
    for (int j = 0; j < FN; ++j) acc[i][j] = (f32x4){0.f, 0.f, 0.f, 0.f};

  uint4 va0h, va0l, va1h, va1l, vb0h, vb0l, vb1h, vb1l;
  va0h = *(const uint4*)(Ah_g + ga0); va0l = *(const uint4*)(Al_g + ga0);
  va1h = *(const uint4*)(Ah_g + ga1); va1l = *(const uint4*)(Al_g + ga1);
  vb0h = *(const uint4*)(Bh_g + gb0); vb0l = *(const uint4*)(Bl_g + gb0);
  if constexpr (BN == 128) {
    vb1h = *(const uint4*)(Bh_g + gb1); vb1l = *(const uint4*)(Bl_g + gb1);
  }

  const int ksteps = K >> 5;
  for (int s = 0; s < ksteps; ++s) {
    __syncthreads();
    *(uint4*)&Ah_s[wa0] = va0h; *(uint4*)&Al_s[wa0] = va0l;
    *(uint4*)&Ah_s[wa1] = va1h; *(uint4*)&Al_s[wa1] = va1l;
    *(uint4*)&Bh_s[wb0] = vb0h; *(uint4*)&Bl_s[wb0] = vb0l;
    if constexpr (BN == 128) {
      *(uint4*)&Bh_s[wb1] = vb1h; *(uint4*)&Bl_s[wb1] = vb1l;
    }
    if (s + 1 < ksteps) {            // issue next-tile loads before MFMA block
      const int k0 = (s + 1) << 5;
      va0h = *(const uint4*)(Ah_g + ga0 + k0); va0l = *(const uint4*)(Al_g + ga0 + k0);
      va1h = *(const uint4*)(Ah_g + ga1 + k0); va1l = *(const uint4*)(Al_g + ga1 + k0);
      vb0h = *(const uint4*)(Bh_g + gb0 + k0); vb0l = *(const uint4*)(Bl_g + gb0 + k0);
      if constexpr (BN == 128) {
        vb1h = *(const uint4*)(Bh_g + gb1 + k0); vb1l = *(const uint4*)(Bl_g + gb1 + k0);
      }
    }
    __syncthreads();
    bf16x8 ah[4], al[4];
#pragma unroll
    for (int i = 0; i < 4; ++i) {
      ah[i] = *(const bf16x8*)&Ah_s[aoff[i]];
      al[i] = *(const bf16x8*)&Al_s[aoff[i]];
    }
#pragma unroll
    for (int j = 0; j < FN; ++j) {
      bf16x8 bh = *(const bf16x8*)&Bh_s[boff[j]];
      bf16x8 bl = *(const bf16x8*)&Bl_s[boff[j]];
#pragma unroll
      for (int i = 0; i < 4; ++i) {
        acc[i][j] = __builtin_amdgcn_mfma_f32_16x16x32_bf16(ah[i], bh, acc[i][j], 0, 0, 0);
        acc[i][j] = __builtin_amdgcn_mfma_f32_16x16x32_bf16(al[i], bh, acc[i][j], 0, 0, 0);
        acc[i][j] = __builtin_amdgcn_mfma_f32_16x16x32_bf16(ah[i], bl, acc[i][j], 0, 0, 0);
      }
    }
  }

  // epilogue: D col=lane&15, row=(lane>>4)*4+reg  [m89-verified layout]
  const int m0 = bm + wm * 64 + ((lane >> 4) << 2);
#pragma unroll
  for (int j = 0; j < FN; ++j) {
    const int n = bn + wn * WN + j * 16 + lr;
    const float bv = bias ? bias[n] : 0.f;
#pragma unroll
    for (int i = 0; i < 4; ++i) {
#pragma unroll
      for (int r = 0; r < 4; ++r) {
        float v = acc[i][j][r] + bv;
        if constexpr (GELU) v = gelu_f(v);
        const size_t off = (size_t)(m0 + i * 16 + r) * N + n;
        if constexpr (SPLITOUT) {
          u16 hh, ll; split_bf(v, hh, ll);
          Ch[off] = hh; Cl[off] = ll;
        } else {
          if (res) v += res[off];     // res/C may alias (in-place residual) -> no restrict
          C[off] = v;
        }
      }
    }
  }
}

// ---- layernorm over D=384; SPLIT=true writes bf16 hi/lo planes (GEMM A-operand)
template<bool SPLIT>
__global__ __launch_bounds__(128) void ln_kernel(const float* __restrict__ in,
                                                 const float* __restrict__ g,
                                                 const float* __restrict__ bb,
                                                 float* __restrict__ out,
                                                 u16* __restrict__ oh, u16* __restrict__ ol)
{
  int row = blockIdx.x, t = threadIdx.x;
  const float* p = in + (size_t)row * ND;
  float v0 = p[t], v1 = p[t + 128], v2 = p[t + 256];
  float s1 = v0 + v1 + v2;
  float s2 = v0 * v0 + v1 * v1 + v2 * v2;
#pragma unroll
  for (int off = 32; off > 0; off >>= 1) {
    s1 += __shfl_down(s1, off);
    s2 += __shfl_down(s2, off);
  }
  __shared__ float sh[4];
  if ((t & 63) == 0) { sh[(t >> 6) * 2] = s1; sh[(t >> 6) * 2 + 1] = s2; }
  __syncthreads();
  float t1 = sh[0] + sh[2], t2 = sh[1] + sh[3];
  float mean = t1 * (1.f / ND);
  float var = t2 * (1.f / ND) - mean * mean;
  float rs = rsqrtf(var + 1e-5f);
  float o0 = (v0 - mean) * rs * g[t]       + bb[t];
  float o1 = (v1 - mean) * rs * g[t + 128] + bb[t + 128];
  float o2 = (v2 - mean) * rs * g[t + 256] + bb[t + 256];
  if constexpr (SPLIT) {
    size_t rb = (size_t)row * ND;
    u16 hh, ll;
    split_bf(o0, hh, ll); oh[rb + t]       = hh; ol[rb + t]       = ll;
    split_bf(o1, hh, ll); oh[rb + t + 128] = hh; ol[rb + t + 128] = ll;
    split_bf(o2, hh, ll); oh[rb + t + 256] = hh; ol[rb + t + 256] = ll;
  } else {
    float* q = out + (size_t)row * ND;
    q[t] = o0; q[t + 128] = o1; q[t + 256] = o2;
  }
}

// ---- per-head [n x 64] = f(in[n][0:64]) @ mat[64][64]
// MODE: 0 plain, 1 relu*SCALE, 2 relu.  SPLIT: write bf16 hi/lo planes.
template<int MODE, bool SPLIT>
__global__ __launch_bounds__(256) void nm_kernel(
    const float* __restrict__ in, const float* __restrict__ mat,
    float* __restrict__ out, u16* __restrict__ oh, u16* __restrict__ ol,
    long sb_in, long sh_in, long sn_in,
    long sb_out, long sh_out, long sn_out,
    long mat_sbh)
{
  int bh = blockIdx.x;   // 0..127
  int nq = blockIdx.y;   // 0..3 (64-row slab)
  int b = bh >> 3, h = bh & 7;
  int t = threadIdx.x;
  __shared__ float ms[4096];      // mat [contract][out]
  __shared__ float xs[16][68];    // staged input rows (padded)
  const float* mp = mat + (size_t)bh * mat_sbh;
#pragma unroll
  for (int i = 0; i < 4; ++i) {
    int idx = t + 256 * i;
    ((float4*)ms)[idx] = ((const float4*)mp)[idx];
  }
  const float* ip = in + (size_t)b * sb_in + (size_t)h * sh_in;
  float* op = nullptr; u16* ohp = nullptr; u16* olp = nullptr;
  if constexpr (SPLIT) {
    ohp = oh + (size_t)b * sb_out + (size_t)h * sh_out;
    olp = ol + (size_t)b * sb_out + (size_t)h * sh_out;
  } else {
    op = out + (size_t)b * sb_out + (size_t)h * sh_out;
  }
  int nr = t >> 4, q4 = (t & 15) * 4;
  for (int p = 0; p < 4; ++p) {
    int nbase = nq * 64 + p * 16 + nr;
    __syncthreads();   // mat staged (p==0) / previous pass's readers done
    float4 v = *(const float4*)(ip + (size_t)nbase * sn_in + q4);
    if (MODE == 1) {
      v.x = fmaxf(v.x, 0.f) * ATT_SCALE; v.y = fmaxf(v.y, 0.f) * ATT_SCALE;
      v.z = fmaxf(v.z, 0.f) * ATT_SCALE; v.w = fmaxf(v.w, 0.f) * ATT_SCALE;
    } else if (MODE == 2) {
      v.x = fmaxf(v.x, 0.f); v.y = fmaxf(v.y, 0.f);
      v.z = fmaxf(v.z, 0.f); v.w = fmaxf(v.w, 0.f);
    }
    *(float4*)&xs[nr][q4] = v;
    __syncthreads();
    float fx = 0.f, fy = 0.f, fz = 0.f, fw = 0.f;
#pragma unroll
    for (int d = 0; d < 64; ++d) {
      float a = xs[nr][d];
      const float4 mm = *(const float4*)&ms[d * 64 + q4];
      fx += a * mm.x; fy += a * mm.y; fz += a * mm.z; fw += a * mm.w;
    }
    if constexpr (SPLIT) {
      u16 h0, l0, h1, l1, h2, l2, h3, l3;
      split_bf(fx, h0, l0); split_bf(fy, h1, l1);
      split_bf(fz, h2, l2); split_bf(fw, h3, l3);
      ushort4 hv; hv.x = h0; hv.y = h1; hv.z = h2; hv.w = h3;
      ushort4 lv; lv.x = l0; lv.y = l1; lv.z = l2; lv.w = l3;
      *(ushort4*)(ohp + (size_t)nbase * sn_out + q4) = hv;
      *(ushort4*)(olp + (size_t)nbase * sn_out + q4) = lv;
    } else {
      float4 o; o.x = fx; o.y = fy; o.z = fz; o.w = fw;
      *(float4*)(op + (size_t)nbase * sn_out + q4) = o;
    }
  }
}

// ---- kv[bh][m][d] = sum_n kp[bh][n][m] * v[b][n][h*64+d]   (v: [4096][512] f32)
__global__ __launch_bounds__(256) void kv_kernel(const float* __restrict__ vq,
                                                 const float* __restrict__ kp,
                                                 float* __restrict__ kvb)
{
  int bh = blockIdx.x;
  int b = bh >> 3, h = bh & 7;
  int t = threadIdx.x;
  __shared__ float ks[16][68];
  __shared__ float vs[16][68];
  int m = t >> 2, dq = t & 3;
  int nr = t >> 4, c4 = (t & 15) * 4;
  const float* vbase = vq + (size_t)b * NW * NIN + h * 64;
  const float* kbase = kp + (size_t)bh * 16384;
  float4 a0 = {0,0,0,0}, a1 = {0,0,0,0}, a2 = {0,0,0,0}, a3 = {0,0,0,0};
  for (int p = 0; p < 16; ++p) {
    __syncthreads();
    *(float4*)&ks[nr][c4] = *(const float4*)(kbase + (size_t)(p * 16 + nr) * 64 + c4);
    *(float4*)&vs[nr][c4] = *(const float4*)(vbase + (size_t)(p * 16 + nr) * NIN + c4);
    __syncthreads();
#pragma unroll
    for (int nn = 0; nn < 16; ++nn) {
      float a = ks[nn][m];
      const float4 v0 = *(const float4*)&vs[nn][dq * 16 + 0];
      const float4 v1 = *(const float4*)&vs[nn][dq * 16 + 4];
      const float4 v2 = *(const float4*)&vs[nn][dq * 16 + 8];
      const float4 v3 = *(const float4*)&vs[nn][dq * 16 + 12];
      a0.x += a * v0.x; a0.y += a * v0.y; a0.z += a * v0.z; a0.w += a * v0.w;
      a1.x += a * v1.x; a1.y += a * v1.y; a1.z += a * v1.z; a1.w += a * v1.w;
      a2.x += a * v2.x; a2.y += a * v2.y; a2.z += a * v2.z; a2.w += a * v2.w;
      a3.x += a * v3.x; a3.y += a * v3.y; a3.z += a * v3.z; a3.w += a * v3.w;
    }
  }
  float* op = kvb + (size_t)bh * 4096 + (size_t)m * 64 + dq * 16;
  *(float4*)(op + 0) = a0; *(float4*)(op + 4) = a1;
  *(float4*)(op + 8) = a2; *(float4*)(op + 12) = a3;
}

// ---- im2col for conv1d k=3 pad=1 -> split planes Acv[4096][1152]
__global__ __launch_bounds__(256) void gather_kernel(const float* __restrict__ h,
                                                     u16* __restrict__ dh, u16* __restrict__ dl)
{
  int idx = blockIdx.x * 256 + threadIdx.x;   // float4 units over [4096][1152]
  if (idx >= 4096 * 288) return;
  int c4 = idx % 288;
  int m = idx / 288;
  int col = c4 * 4;
  int j = col / 384;
  int d = col - j * 384;
  int n = m & 255;
  int nn = n + j - 1;
  float4 v = {0, 0, 0, 0};
  if (nn >= 0 && nn < 256) v = *(const float4*)(h + (size_t)(m + j - 1) * ND + d);
  u16 h0, l0, h1, l1, h2, l2, h3, l3;
  split_bf(v.x, h0, l0); split_bf(v.y, h1, l1);
  split_bf(v.z, h2, l2); split_bf(v.w, h3, l3);
  ushort4 hv; hv.x = h0; hv.y = h1; hv.z = h2; hv.w = h3;
  ushort4 lv; lv.x = l0; lv.y = l1; lv.z = l2; lv.w = l3;
  size_t off = (size_t)m * 1152 + col;
  *(ushort4*)(dh + off) = hv;
  *(ushort4*)(dl + off) = lv;
}

// ---- final: out[b][c][l] = lerp(hp[b][i0][c], hp[b][i1][c]) + x[b][c][l]
__global__ __launch_bounds__(256) void final_kernel(const float* __restrict__ hp,
                                                    const float* __restrict__ x,
                                                    float* __restrict__ out)
{
  size_t idx = (size_t)blockIdx.x * 256 + threadIdx.x;   // float4 index
  int l4 = (int)(idx & 1023);
  int c  = (int)((idx >> 10) & 511);
  int b  = (int)(idx >> 19);
  const float4 xv = ((const float4*)x)[idx];
  float xr[4] = {xv.x, xv.y, xv.z, xv.w};
  float ov[4];
  const float* hpb = hp + (size_t)b * NW * NIN + c;
#pragma unroll
  for (int j = 0; j < 4; ++j) {
    int l = l4 * 4 + j;
    float src = fmaxf((l + 0.5f) * (1.f / 16.f) - 0.5f, 0.f);
    int i0 = (int)src; if (i0 > 255) i0 = 255;
    int i1 = i0 + 1; if (i1 > 255) i1 = 255;
    float w = src - (float)i0;
    float a = hpb[(size_t)i0 * NIN];
    float b2 = hpb[(size_t)i1 * NIN];
    ov[j] = a + (b2 - a) * w + xr[j];
  }
  float4 res; res.x = ov[0]; res.y = ov[1]; res.z = ov[2]; res.w = ov[3];
  ((float4*)out)[idx] = res;
}

extern "C" void kernel_launch(void* const* d_in, const int* in_sizes, int n_in,
                              void* d_out, int out_size, void* d_ws, size_t ws_size,
                              hipStream_t stream)
{
  const float* x          = (const float*)d_in[0];
  const float* proj_in_w  = (const float*)d_in[1];
  const float* proj_in_b  = (const float*)d_in[2];
  const float* norm_in_g  = (const float*)d_in[3];
  const float* norm_in_b  = (const float*)d_in[4];
  const float* ln1_g      = (const float*)d_in[5];
  const float* ln1_b      = (const float*)d_in[6];
  const float* wqkv       = (const float*)d_in[7];
  const float* rf         = (const float*)d_in[8];
  const float* wout       = (const float*)d_in[9];
  const float* bout       = (const float*)d_in[10];
  const float* ln2_g      = (const float*)d_in[11];
  const float* ln2_b      = (const float*)d_in[12];
  const float* ffw1       = (const float*)d_in[13];
  const float* ffb1       = (const float*)d_in[14];
  const float* ffw2       = (const float*)d_in[15];
  const float* ffb2       = (const float*)d_in[16];
  const float* local_w    = (const float*)d_in[17];
  const float* local_b    = (const float*)d_in[18];
  const float* norm_out_g = (const float*)d_in[19];
  const float* norm_out_b = (const float*)d_in[20];
  const float* proj_out_w = (const float*)d_in[21];
  const float* proj_out_b = (const float*)d_in[22];
  float* out = (float*)d_out;

  // ---- workspace layout (bytes; total used 47,710,208 <= 48 MiB) ----
  char* const base = (char*)d_ws;
  float* const hbuf = (float*)base;                      // [4096][384] f32, persistent
  // per-layer weight slots (split-bf16, transposed to [N][K])
  u16* const wqh   = (u16*)(base + 6291456);             // wqkvT [1536][384]
  u16* const wql   = wqh + 589824;
  u16* const woh   = wql + 589824;                       // woutT [384][512]
  u16* const wol   = woh + 196608;
  u16* const f1h_w = wol + 196608;                       // ffw1T [1536][384]
  u16* const f1l_w = f1h_w + 589824;
  u16* const f2h_w = f1l_w + 589824;                     // ffw2T [384][1536]
  u16* const f2l_w = f2h_w + 589824;
  char* const P = base + 14155776;                       // phase pool (34.5 MiB)
  // pool slots (phase-overlaid)
  u16* const ybh   = (u16*)P;                            // ln-out planes [4096][384]
  u16* const ybl   = ybh + 1572864;
  float* const slotQ = (float*)(P + 6291456);            // q/k/v f32 [4096][512] (time-shared)
  float* const qpb = (float*)(P + 14680064);             // [128][256][64]
  float* const kpb = (float*)(P + 23068672);             // [128][256][64]
  float* const kvb = (float*)(P + 31457280);             // [128][64][64]
  u16* const oh    = (u16*)(P + 23068672);               // attn-o planes [4096][512] (over kpb)
  u16* const ol    = oh + 2097152;
  u16* const f1oh  = (u16*)(P + 6291456);                // ff1-out planes [4096][1536]
  u16* const f1ol  = f1oh + 6291456;
  u16* const avh   = (u16*)(P + 6291456);                // im2col planes [4096][1152]
  u16* const avl   = avh + 4718592;
  u16* const cwh   = (u16*)(P + 25165824);               // convw planes [384][1152]
  u16* const cwl   = cwh + 442368;
  u16* const xph   = (u16*)(P + 6291456);                // pooled planes [4096][512]
  u16* const xpl   = xph + 2097152;
  u16* const pih   = (u16*)(P + 14680064);               // proj_in_w planes [384][512]
  u16* const pil   = pih + 196608;
  float* const ypre = (float*)(P + 15466496);            // [4096][384] f32
  u16* const poh   = (u16*)(P + 6291456);                // proj_out_w planes [512][384]
  u16* const pol   = poh + 196608;
  float* const hp  = (float*)(P + 7077888);              // [4096][512] f32

  // ---- setup: pool + proj_in + LN_in ----
  pool_kernel<<<8192, 256, 0, stream>>>(x, xph, xpl);
  split_kernel<<<768, 256, 0, stream>>>(proj_in_w, pih, pil, 196608);
  mgemm<64, false, false><<<dim3(6, 32), 256, 0, stream>>>(
      xph, xpl, pih, pil, proj_in_b, nullptr, ypre, nullptr, nullptr, 384, 512);
  ln_kernel<false><<<4096, 128, 0, stream>>>(ypre, norm_in_g, norm_in_b, hbuf, nullptr, nullptr);

  for (int i = 0; i < 2; ++i) {
    // weight split+transpose for this layer
    tsplit_kernel<<<dim3(48, 12), 256, 0, stream>>>(wqkv + (size_t)i * 589824, wqh, wql, 384, 1536);
    tsplit_kernel<<<dim3(12, 16), 256, 0, stream>>>(wout + (size_t)i * 196608, woh, wol, 512, 384);
    tsplit_kernel<<<dim3(48, 12), 256, 0, stream>>>(ffw1 + (size_t)i * 589824, f1h_w, f1l_w, 384, 1536);
    tsplit_kernel<<<dim3(12, 48), 256, 0, stream>>>(ffw2 + (size_t)i * 589824, f2h_w, f2l_w, 1536, 384);

    ln_kernel<true><<<4096, 128, 0, stream>>>(hbuf, ln1_g + i * 384, ln1_b + i * 384,
                                              nullptr, ybh, ybl);
    // q proj -> qp
    mgemm<64, false, false><<<dim3(8, 32), 256, 0, stream>>>(
        ybh, ybl, wqh, wql, nullptr, nullptr, slotQ, nullptr, nullptr, 512, 384);
    nm_kernel<1, false><<<dim3(128, 4), 256, 0, stream>>>(slotQ, rf + (size_t)i * 4096,
        qpb, nullptr, nullptr, 131072L, 64L, 512L, 131072L, 16384L, 64L, 0L);
    // k proj -> kp
    mgemm<64, false, false><<<dim3(8, 32), 256, 0, stream>>>(
        ybh, ybl, wqh + 196608, wql + 196608, nullptr, nullptr, slotQ, nullptr, nullptr, 512, 384);
    nm_kernel<2, false><<<dim3(128, 4), 256, 0, stream>>>(slotQ, rf + (size_t)i * 4096,
        kpb, nullptr, nullptr, 131072L, 64L, 512L, 131072L, 16384L, 64L, 0L);
    // v proj
    mgemm<64, false, false><<<dim3(8, 32), 256, 0, stream>>>(
        ybh, ybl, wqh + 393216, wql + 393216, nullptr, nullptr, slotQ, nullptr, nullptr, 512, 384);
    // kv = kp^T @ v ; o = qp @ kv (split planes)
    kv_kernel<<<128, 256, 0, stream>>>(slotQ, kpb, kvb);
    nm_kernel<0, true><<<dim3(128, 4), 256, 0, stream>>>(qpb, kvb, nullptr, oh, ol,
        131072L, 16384L, 64L, 131072L, 64L, 512L, 4096L);
    // h += o @ wout + bout
    mgemm<64, false, false><<<dim3(6, 32), 256, 0, stream>>>(
        oh, ol, woh, wol, bout + i * 384, hbuf, hbuf, nullptr, nullptr, 384, 512);
    // FF
    ln_kernel<true><<<4096, 128, 0, stream>>>(hbuf, ln2_g + i * 384, ln2_b + i * 384,
                                              nullptr, ybh, ybl);
    mgemm<128, true, true><<<dim3(12, 32), 256, 0, stream>>>(
        ybh, ybl, f1h_w, f1l_w, ffb1 + i * 1536, nullptr, nullptr, f1oh, f1ol, 1536, 384);
    mgemm<64, false, false><<<dim3(6, 32), 256, 0, stream>>>(
        f1oh, f1ol, f2h_w, f2l_w, ffb2 + i * 384, hbuf, hbuf, nullptr, nullptr, 384, 1536);
  }

  // ---- local conv (im2col planes @ convw planes, residual into hbuf) ----
  convw_split_kernel<<<1728, 256, 0, stream>>>(local_w, cwh, cwl);
  gather_kernel<<<4608, 256, 0, stream>>>(hbuf, avh, avl);
  mgemm<64, false, false><<<dim3(6, 32), 256, 0, stream>>>(
      avh, avl, cwh, cwl, local_b, hbuf, hbuf, nullptr, nullptr, 384, 1152);

  // ---- LN_out + proj_out folded before interpolation ----
  ln_kernel<true><<<4096, 128, 0, stream>>>(hbuf, norm_out_g, norm_out_b, nullptr, ybh, ybl);
  split_kernel<<<768, 256, 0, stream>>>(proj_out_w, poh, pol, 196608);
  mgemm<64, false, false><<<dim3(8, 32), 256, 0, stream>>>(
      ybh, ybl, poh, pol, proj_out_b, nullptr, hp, nullptr, nullptr, 512, 384);

  // ---- interp + residual ----
  final_kernel<<<32768, 256, 0, stream>>>(hp, x, out);
}

// Round 2
// 853.494 us; speedup vs baseline: 1.5804x; 1.0694x over previous
//
#include <hip/hip_runtime.h>
#include <math.h>

typedef unsigned short u16;
typedef unsigned int u32;
typedef __bf16 bf16;
typedef __attribute__((ext_vector_type(8))) __bf16 bf16x8;
typedef __attribute__((ext_vector_type(4))) float f32x4;

#define NB 16
#define NC 512
#define NL 4096
#define ND 384
#define NW 256      // pooled length n
#define NIN 512     // inner
#define NFF 1536
#define NM (NB*NW)  // 4096 rows
#define ATT_SCALE 0.125f

__device__ __forceinline__ float gelu_f(float x) {
  return 0.5f * x * (1.f + erff(x * 0.70710678118654752f));
}

// ---- fp32 -> bf16 hi/lo split (RNE via bit math; lo = exact residual rounded)
__device__ __forceinline__ u16 bf_hi(float f) {
  u32 u = __float_as_uint(f);
  u32 r = u + 0x7FFFu + ((u >> 16) & 1u);
  return (u16)(r >> 16);
}
__device__ __forceinline__ float bf_f(u16 h) { return __uint_as_float((u32)h << 16); }
__device__ __forceinline__ void split_bf(float f, u16& h, u16& l) {
  h = bf_hi(f);
  l = bf_hi(f - bf_f(h));
}

// ---- pool: x[b][c][0:4096] -> mean over 16 -> split-bf16 planes xpT[(b*256+n)][c]
__global__ __launch_bounds__(256) void pool_kernel(const float* __restrict__ x,
                                                   u16* __restrict__ xh, u16* __restrict__ xl) {
  int blk = blockIdx.x;            // b*512 + c
  int b = blk >> 9, c = blk & 511;
  int t = threadIdx.x;             // window index n
  const float4* p = (const float4*)(x + (size_t)blk * NL) + t * 4;
  float s = 0.f;
#pragma unroll
  for (int i = 0; i < 4; ++i) {
    float4 v = p[i];
    s += v.x + v.y + v.z + v.w;
  }
  u16 hh, ll; split_bf(s * (1.f / 16.f), hh, ll);
  size_t off = ((size_t)b * NW + t) * NC + c;
  xh[off] = hh; xl[off] = ll;
}

// ---- elementwise split (weights already in [N][K] layout)
__global__ __launch_bounds__(256) void split_kernel(const float* __restrict__ src,
                                                    u16* __restrict__ dh, u16* __restrict__ dl, int n) {
  int i = blockIdx.x * 256 + threadIdx.x;
  if (i >= n) return;
  u16 h, l; split_bf(src[i], h, l);
  dh[i] = h; dl[i] = l;
}

// ---- transpose+split: src[R][C] f32 -> dst planes [C][R] bf16 (dst[c][r]=src[r][c])
__global__ __launch_bounds__(256) void tsplit_kernel(const float* __restrict__ src,
                                                     u16* __restrict__ dh, u16* __restrict__ dl,
                                                     int R, int C) {
  __shared__ float tile[32][33];
  const int tc = blockIdx.x * 32, tr = blockIdx.y * 32;
  const int lx = threadIdx.x & 31, ly = threadIdx.x >> 5;   // 32 x 8
#pragma unroll
  for (int p = 0; p < 4; ++p)
    tile[ly + p * 8][lx] = src[(size_t)(tr + ly + p * 8) * C + tc + lx];
  __syncthreads();
#pragma unroll
  for (int p = 0; p < 4; ++p) {
    const int c = tc + ly + p * 8;
    const float v = tile[lx][ly + p * 8];
    u16 h, l; split_bf(v, h, l);
    dh[(size_t)c * R + tr + lx] = h;
    dl[(size_t)c * R + tr + lx] = l;
  }
}

// ---- conv weight: BT[n=dout][k=j*384+dp] = local_w[dout][dp][j], split planes
__global__ __launch_bounds__(256) void convw_split_kernel(const float* __restrict__ lw,
                                                          u16* __restrict__ dh, u16* __restrict__ dl) {
  int idx = blockIdx.x * 256 + threadIdx.x;       // over 384*1152
  if (idx >= 384 * 1152) return;
  int n = idx / 1152, k = idx - n * 1152;
  int j = k / 384, dp = k - j * 384;
  u16 h, l; split_bf(lw[(size_t)n * 1152 + dp * 3 + j], h, l);
  dh[idx] = h; dl[idx] = l;
}

// ---- MFMA split-bf16 GEMM.  C[m][n] = f(A@B^T + bias) (+res)
// A planes: [M][K] bf16 hi/lo.  B planes: [N][K] bf16 hi/lo (pre-transposed weights).
// BM=128 fixed, BN in {64,128}. 256 threads = 4 waves (2x2), wave tile 64 x BN/2.
// LDS tiles [rows][32] bf16, XOR-swizzle byte^=((row&7)<<4) -> <=2-way bank conflicts (free).
// 3-product emulation: acc += Ah*Bh + Al*Bh + Ah*Bl  (drops Al*Bl ~ 2^-18 rel).
template<int BN, bool GELU, bool SPLITOUT>
__global__ __launch_bounds__(256) void mgemm(
    const u16* __restrict__ Ah_g, const u16* __restrict__ Al_g,
    const u16* __restrict__ Bh_g, const u16* __restrict__ Bl_g,
    const float* __restrict__ bias, const float* res,
    float* C, u16* Ch, u16* Cl, int N, int K)
{
  constexpr int FN = BN / 32;
  constexpr int WN = BN / 2;
  __shared__ __align__(16) u16 Ah_s[128 * 32], Al_s[128 * 32];
  __shared__ __align__(16) u16 Bh_s[BN * 32],  Bl_s[BN * 32];

  const int t = threadIdx.x;
  const int bm = blockIdx.y * 128;
  const int bn = blockIdx.x * BN;

  // staging: 16B chunks; A has 512 chunks (2/thread), B has BN*4 chunks
  const int ra0 = t >> 2, ra1 = ra0 + 64;
  const int ca = (t & 3) * 8;
  const size_t ga0 = (size_t)(bm + ra0) * K + ca;
  const size_t ga1 = (size_t)(bm + ra1) * K + ca;
  const int wa0 = (ra0 * 32 + ca) ^ ((ra0 & 7) << 3);
  const int wa1 = (ra1 * 32 + ca) ^ ((ra1 & 7) << 3);
  const size_t gb0 = (size_t)(bn + ra0) * K + ca;
  const int wb0 = wa0;
  size_t gb1 = 0; int wb1 = 0;
  if constexpr (BN == 128) { gb1 = (size_t)(bn + ra1) * K + ca; wb1 = wa1; }

  // fragment offsets (A: row=lane&15, k=(lane>>4)*8+e ; B symmetric on [N][K])
  const int lane = t & 63;
  const int w = t >> 6, wm = w >> 1, wn = w & 1;
  const int lr = lane & 15;
  const int kb = (lane >> 4) << 3;
  int aoff[4], boff[FN];
#pragma unroll
  for (int i = 0; i < 4; ++i) {
    int r = wm * 64 + i * 16 + lr;
    aoff[i] = (r * 32 + kb) ^ ((r & 7) << 3);
  }
#pragma unroll
  for (int j = 0; j < FN; ++j) {
    int r = wn * WN + j * 16 + lr;
    boff[j] = (r * 32 + kb) ^ ((r & 7) << 3);
  }

  f32x4 acc[4][FN];
#pragma unroll
  for (int i = 0; i < 4; ++i)
#pragma unroll
    for (int j = 0; j < FN; ++j) acc[i][j] = (f32x4){0.f, 0.f, 0.f, 0.f};

  uint4 va0h, va0l, va1h, va1l, vb0h, vb0l, vb1h, vb1l;
  va0h = *(const uint4*)(Ah_g + ga0); va0l = *(const uint4*)(Al_g + ga0);
  va1h = *(const uint4*)(Ah_g + ga1); va1l = *(const uint4*)(Al_g + ga1);
  vb0h = *(const uint4*)(Bh_g + gb0); vb0l = *(const uint4*)(Bl_g + gb0);
  if constexpr (BN == 128) {
    vb1h = *(const uint4*)(Bh_g + gb1); vb1l = *(const uint4*)(Bl_g + gb1);
  }

  const int ksteps = K >> 5;
  for (int s = 0; s < ksteps; ++s) {
    __syncthreads();
    *(uint4*)&Ah_s[wa0] = va0h; *(uint4*)&Al_s[wa0] = va0l;
    *(uint4*)&Ah_s[wa1] = va1h; *(uint4*)&Al_s[wa1] = va1l;
    *(uint4*)&Bh_s[wb0] = vb0h; *(uint4*)&Bl_s[wb0] = vb0l;
    if constexpr (BN == 128) {
      *(uint4*)&Bh_s[wb1] = vb1h; *(uint4*)&Bl_s[wb1] = vb1l;
    }
    if (s + 1 < ksteps) {            // issue next-tile loads before MFMA block
      const int k0 = (s + 1) << 5;
      va0h = *(const uint4*)(Ah_g + ga0 + k0); va0l = *(const uint4*)(Al_g + ga0 + k0);
      va1h = *(const uint4*)(Ah_g + ga1 + k0); va1l = *(const uint4*)(Al_g + ga1 + k0);
      vb0h = *(const uint4*)(Bh_g + gb0 + k0); vb0l = *(const uint4*)(Bl_g + gb0 + k0);
      if constexpr (BN == 128) {
        vb1h = *(const uint4*)(Bh_g + gb1 + k0); vb1l = *(const uint4*)(Bl_g + gb1 + k0);
      }
    }
    __syncthreads();
    bf16x8 ah[4], al[4];
#pragma unroll
    for (int i = 0; i < 4; ++i) {
      ah[i] = *(const bf16x8*)&Ah_s[aoff[i]];
      al[i] = *(const bf16x8*)&Al_s[aoff[i]];
    }
#pragma unroll
    for (int j = 0; j < FN; ++j) {
      bf16x8 bh = *(const bf16x8*)&Bh_s[boff[j]];
      bf16x8 bl = *(const bf16x8*)&Bl_s[boff[j]];
#pragma unroll
      for (int i = 0; i < 4; ++i) {
        acc[i][j] = __builtin_amdgcn_mfma_f32_16x16x32_bf16(ah[i], bh, acc[i][j], 0, 0, 0);
        acc[i][j] = __builtin_amdgcn_mfma_f32_16x16x32_bf16(al[i], bh, acc[i][j], 0, 0, 0);
        acc[i][j] = __builtin_amdgcn_mfma_f32_16x16x32_bf16(ah[i], bl, acc[i][j], 0, 0, 0);
      }
    }
  }

  // epilogue: D col=lane&15, row=(lane>>4)*4+reg  [m89-verified layout]
  const int m0 = bm + wm * 64 + ((lane >> 4) << 2);
#pragma unroll
  for (int j = 0; j < FN; ++j) {
    const int n = bn + wn * WN + j * 16 + lr;
    const float bv = bias ? bias[n] : 0.f;
#pragma unroll
    for (int i = 0; i < 4; ++i) {
#pragma unroll
      for (int r = 0; r < 4; ++r) {
        float v = acc[i][j][r] + bv;
        if constexpr (GELU) v = gelu_f(v);
        const size_t off = (size_t)(m0 + i * 16 + r) * N + n;
        if constexpr (SPLITOUT) {
          u16 hh, ll; split_bf(v, hh, ll);
          Ch[off] = hh; Cl[off] = ll;
        } else {
          if (res) v += res[off];     // res/C may alias (in-place residual) -> no restrict
          C[off] = v;
        }
      }
    }
  }
}

// ---- layernorm over D=384; SPLIT=true writes bf16 hi/lo planes (GEMM A-operand)
template<bool SPLIT>
__global__ __launch_bounds__(128) void ln_kernel(const float* __restrict__ in,
                                                 const float* __restrict__ g,
                                                 const float* __restrict__ bb,
                                                 float* __restrict__ out,
                                                 u16* __restrict__ oh, u16* __restrict__ ol)
{
  int row = blockIdx.x, t = threadIdx.x;
  const float* p = in + (size_t)row * ND;
  float v0 = p[t], v1 = p[t + 128], v2 = p[t + 256];
  float s1 = v0 + v1 + v2;
  float s2 = v0 * v0 + v1 * v1 + v2 * v2;
#pragma unroll
  for (int off = 32; off > 0; off >>= 1) {
    s1 += __shfl_down(s1, off);
    s2 += __shfl_down(s2, off);
  }
  __shared__ float sh[4];
  if ((t & 63) == 0) { sh[(t >> 6) * 2] = s1; sh[(t >> 6) * 2 + 1] = s2; }
  __syncthreads();
  float t1 = sh[0] + sh[2], t2 = sh[1] + sh[3];
  float mean = t1 * (1.f / ND);
  float var = t2 * (1.f / ND) - mean * mean;
  float rs = rsqrtf(var + 1e-5f);
  float o0 = (v0 - mean) * rs * g[t]       + bb[t];
  float o1 = (v1 - mean) * rs * g[t + 128] + bb[t + 128];
  float o2 = (v2 - mean) * rs * g[t + 256] + bb[t + 256];
  if constexpr (SPLIT) {
    size_t rb = (size_t)row * ND;
    u16 hh, ll;
    split_bf(o0, hh, ll); oh[rb + t]       = hh; ol[rb + t]       = ll;
    split_bf(o1, hh, ll); oh[rb + t + 128] = hh; ol[rb + t + 128] = ll;
    split_bf(o2, hh, ll); oh[rb + t + 256] = hh; ol[rb + t + 256] = ll;
  } else {
    float* q = out + (size_t)row * ND;
    q[t] = o0; q[t + 128] = o1; q[t + 256] = o2;
  }
}

// ---- per-head [n x 64] = f(in[n][0:64]) @ mat[64][64]
// MODE: 0 plain, 1 relu*SCALE, 2 relu.  SPLIT: write bf16 hi/lo planes.
template<int MODE, bool SPLIT>
__global__ __launch_bounds__(256) void nm_kernel(
    const float* __restrict__ in, const float* __restrict__ mat,
    float* __restrict__ out, u16* __restrict__ oh, u16* __restrict__ ol,
    long sb_in, long sh_in, long sn_in,
    long sb_out, long sh_out, long sn_out,
    long mat_sbh)
{
  int bh = blockIdx.x;   // 0..127
  int nq = blockIdx.y;   // 0..3 (64-row slab)
  int b = bh >> 3, h = bh & 7;
  int t = threadIdx.x;
  __shared__ float ms[4096];      // mat [contract][out]
  __shared__ float xs[16][68];    // staged input rows (padded)
  const float* mp = mat + (size_t)bh * mat_sbh;
#pragma unroll
  for (int i = 0; i < 4; ++i) {
    int idx = t + 256 * i;
    ((float4*)ms)[idx] = ((const float4*)mp)[idx];
  }
  const float* ip = in + (size_t)b * sb_in + (size_t)h * sh_in;
  float* op = nullptr; u16* ohp = nullptr; u16* olp = nullptr;
  if constexpr (SPLIT) {
    ohp = oh + (size_t)b * sb_out + (size_t)h * sh_out;
    olp = ol + (size_t)b * sb_out + (size_t)h * sh_out;
  } else {
    op = out + (size_t)b * sb_out + (size_t)h * sh_out;
  }
  int nr = t >> 4, q4 = (t & 15) * 4;
  for (int p = 0; p < 4; ++p) {
    int nbase = nq * 64 + p * 16 + nr;
    __syncthreads();   // mat staged (p==0) / previous pass's readers done
    float4 v = *(const float4*)(ip + (size_t)nbase * sn_in + q4);
    if (MODE == 1) {
      v.x = fmaxf(v.x, 0.f) * ATT_SCALE; v.y = fmaxf(v.y, 0.f) * ATT_SCALE;
      v.z = fmaxf(v.z, 0.f) * ATT_SCALE; v.w = fmaxf(v.w, 0.f) * ATT_SCALE;
    } else if (MODE == 2) {
      v.x = fmaxf(v.x, 0.f); v.y = fmaxf(v.y, 0.f);
      v.z = fmaxf(v.z, 0.f); v.w = fmaxf(v.w, 0.f);
    }
    *(float4*)&xs[nr][q4] = v;
    __syncthreads();
    float fx = 0.f, fy = 0.f, fz = 0.f, fw = 0.f;
#pragma unroll
    for (int d = 0; d < 64; ++d) {
      float a = xs[nr][d];
      const float4 mm = *(const float4*)&ms[d * 64 + q4];
      fx += a * mm.x; fy += a * mm.y; fz += a * mm.z; fw += a * mm.w;
    }
    if constexpr (SPLIT) {
      u16 h0, l0, h1, l1, h2, l2, h3, l3;
      split_bf(fx, h0, l0); split_bf(fy, h1, l1);
      split_bf(fz, h2, l2); split_bf(fw, h3, l3);
      ushort4 hv; hv.x = h0; hv.y = h1; hv.z = h2; hv.w = h3;
      ushort4 lv; lv.x = l0; lv.y = l1; lv.z = l2; lv.w = l3;
      *(ushort4*)(ohp + (size_t)nbase * sn_out + q4) = hv;
      *(ushort4*)(olp + (size_t)nbase * sn_out + q4) = lv;
    } else {
      float4 o; o.x = fx; o.y = fy; o.z = fz; o.w = fw;
      *(float4*)(op + (size_t)nbase * sn_out + q4) = o;
    }
  }
}

// ---- kv[bh][m][d] = sum_n kp[bh][n][m] * v[b][n][h*64+d]   (v: [4096][512] f32)
__global__ __launch_bounds__(256) void kv_kernel(const float* __restrict__ vq,
                                                 const float* __restrict__ kp,
                                                 float* __restrict__ kvb)
{
  int bh = blockIdx.x;
  int b = bh >> 3, h = bh & 7;
  int t = threadIdx.x;
  __shared__ float ks[16][68];
  __shared__ float vs[16][68];
  int m = t >> 2, dq = t & 3;
  int nr = t >> 4, c4 = (t & 15) * 4;
  const float* vbase = vq + (size_t)b * NW * NIN + h * 64;
  const float* kbase = kp + (size_t)bh * 16384;
  float4 a0 = {0,0,0,0}, a1 = {0,0,0,0}, a2 = {0,0,0,0}, a3 = {0,0,0,0};
  for (int p = 0; p < 16; ++p) {
    __syncthreads();
    *(float4*)&ks[nr][c4] = *(const float4*)(kbase + (size_t)(p * 16 + nr) * 64 + c4);
    *(float4*)&vs[nr][c4] = *(const float4*)(vbase + (size_t)(p * 16 + nr) * NIN + c4);
    __syncthreads();
#pragma unroll
    for (int nn = 0; nn < 16; ++nn) {
      float a = ks[nn][m];
      const float4 v0 = *(const float4*)&vs[nn][dq * 16 + 0];
      const float4 v1 = *(const float4*)&vs[nn][dq * 16 + 4];
      const float4 v2 = *(const float4*)&vs[nn][dq * 16 + 8];
      const float4 v3 = *(const float4*)&vs[nn][dq * 16 + 12];
      a0.x += a * v0.x; a0.y += a * v0.y; a0.z += a * v0.z; a0.w += a * v0.w;
      a1.x += a * v1.x; a1.y += a * v1.y; a1.z += a * v1.z; a1.w += a * v1.w;
      a2.x += a * v2.x; a2.y += a * v2.y; a2.z += a * v2.z; a2.w += a * v2.w;
      a3.x += a * v3.x; a3.y += a * v3.y; a3.z += a * v3.z; a3.w += a * v3.w;
    }
  }
  float* op = kvb + (size_t)bh * 4096 + (size_t)m * 64 + dq * 16;
  *(float4*)(op + 0) = a0; *(float4*)(op + 4) = a1;
  *(float4*)(op + 8) = a2; *(float4*)(op + 12) = a3;
}

// ---- im2col for conv1d k=3 pad=1 -> split planes Acv[4096][1152]
__global__ __launch_bounds__(256) void gather_kernel(const float* __restrict__ h,
                                                     u16* __restrict__ dh, u16* __restrict__ dl)
{
  int idx = blockIdx.x * 256 + threadIdx.x;   // float4 units over [4096][1152]
  if (idx >= 4096 * 288) return;
  int c4 = idx % 288;
  int m = idx / 288;
  int col = c4 * 4;
  int j = col / 384;
  int d = col - j * 384;
  int n = m & 255;
  int nn = n + j - 1;
  float4 v = {0, 0, 0, 0};
  if (nn >= 0 && nn < 256) v = *(const float4*)(h + (size_t)(m + j - 1) * ND + d);
  u16 h0, l0, h1, l1, h2, l2, h3, l3;
  split_bf(v.x, h0, l0); split_bf(v.y, h1, l1);
  split_bf(v.z, h2, l2); split_bf(v.w, h3, l3);
  ushort4 hv; hv.x = h0; hv.y = h1; hv.z = h2; hv.w = h3;
  ushort4 lv; lv.x = l0; lv.y = l1; lv.z = l2; lv.w = l3;
  size_t off = (size_t)m * 1152 + col;
  *(ushort4*)(dh + off) = hv;
  *(ushort4*)(dl + off) = lv;
}

// ---- final: one block per (b,c) row. Stage hp[b][0:256][c] in LDS once,
// then each thread owns one aligned 16-sample output group with COMPILE-TIME
// interp weights: out[l=g*16+r] = lerp(hp[g-1|g], hp[g|g+1], w(r)) + x[b][c][l].
// Index clamp at g=0 / g=255 reproduces the reference edge behavior exactly
// (h0==h1 -> lerp degenerates to the constant).
// VMEM per thread: 1 scalar + 4 float4 loads + 4 float4 stores for 16 outputs
// (was 10 VMEM per 4 outputs -> issue-bound at 126us).
__global__ __launch_bounds__(256) void final_kernel(const float* __restrict__ hp,
                                                    const float* __restrict__ x,
                                                    float* __restrict__ out)
{
  __shared__ float ls[256];
  const int blk = blockIdx.x;      // b*512 + c
  const int b = blk >> 9, c = blk & 511;
  const int t = threadIdx.x;       // group index g = pooled position n
  ls[t] = hp[((size_t)b * NW + t) * NIN + c];
  __syncthreads();
  const float h0 = ls[t == 0 ? 0 : t - 1];
  const float h1 = ls[t];
  const float h2 = ls[t == 255 ? 255 : t + 1];
  const float d01 = h1 - h0, d12 = h2 - h1;
  float o[16];
#pragma unroll
  for (int r = 0; r < 8; ++r) o[r]     = h0 + d01 * ((r + 8.5f) * 0.0625f);
#pragma unroll
  for (int r = 0; r < 8; ++r) o[r + 8] = h1 + d12 * ((r + 0.5f) * 0.0625f);
  const float4* xp = (const float4*)(x + (size_t)blk * NL + t * 16);
  float4* op = (float4*)(out + (size_t)blk * NL + t * 16);
#pragma unroll
  for (int j = 0; j < 4; ++j) {
    float4 xv = xp[j];
    float4 res;
    res.x = o[j * 4 + 0] + xv.x;
    res.y = o[j * 4 + 1] + xv.y;
    res.z = o[j * 4 + 2] + xv.z;
    res.w = o[j * 4 + 3] + xv.w;
    op[j] = res;
  }
}

extern "C" void kernel_launch(void* const* d_in, const int* in_sizes, int n_in,
                              void* d_out, int out_size, void* d_ws, size_t ws_size,
                              hipStream_t stream)
{
  const float* x          = (const float*)d_in[0];
  const float* proj_in_w  = (const float*)d_in[1];
  const float* proj_in_b  = (const float*)d_in[2];
  const float* norm_in_g  = (const float*)d_in[3];
  const float* norm_in_b  = (const float*)d_in[4];
  const float* ln1_g      = (const float*)d_in[5];
  const float* ln1_b      = (const float*)d_in[6];
  const float* wqkv       = (const float*)d_in[7];
  const float* rf         = (const float*)d_in[8];
  const float* wout       = (const float*)d_in[9];
  const float* bout       = (const float*)d_in[10];
  const float* ln2_g      = (const float*)d_in[11];
  const float* ln2_b      = (const float*)d_in[12];
  const float* ffw1       = (const float*)d_in[13];
  const float* ffb1       = (const float*)d_in[14];
  const float* ffw2       = (const float*)d_in[15];
  const float* ffb2       = (const float*)d_in[16];
  const float* local_w    = (const float*)d_in[17];
  const float* local_b    = (const float*)d_in[18];
  const float* norm_out_g = (const float*)d_in[19];
  const float* norm_out_b = (const float*)d_in[20];
  const float* proj_out_w = (const float*)d_in[21];
  const float* proj_out_b = (const float*)d_in[22];
  float* out = (float*)d_out;

  // ---- workspace layout (bytes; total used 47,710,208 <= 48 MiB) ----
  char* const base = (char*)d_ws;
  float* const hbuf = (float*)base;                      // [4096][384] f32, persistent
  // per-layer weight slots (split-bf16, transposed to [N][K])
  u16* const wqh   = (u16*)(base + 6291456);             // wqkvT [1536][384]
  u16* const wql   = wqh + 589824;
  u16* const woh   = wql + 589824;                       // woutT [384][512]
  u16* const wol   = woh + 196608;
  u16* const f1h_w = wol + 196608;                       // ffw1T [1536][384]
  u16* const f1l_w = f1h_w + 589824;
  u16* const f2h_w = f1l_w + 589824;                     // ffw2T [384][1536]
  u16* const f2l_w = f2h_w + 589824;
  char* const P = base + 14155776;                       // phase pool (34.5 MiB)
  // pool slots (phase-overlaid)
  u16* const ybh   = (u16*)P;                            // ln-out planes [4096][384]
  u16* const ybl   = ybh + 1572864;
  float* const slotQ = (float*)(P + 6291456);            // q/k/v f32 [4096][512] (time-shared)
  float* const qpb = (float*)(P + 14680064);             // [128][256][64]
  float* const kpb = (float*)(P + 23068672);             // [128][256][64]
  float* const kvb = (float*)(P + 31457280);             // [128][64][64]
  u16* const oh    = (u16*)(P + 23068672);               // attn-o planes [4096][512] (over kpb)
  u16* const ol    = oh + 2097152;
  u16* const f1oh  = (u16*)(P + 6291456);                // ff1-out planes [4096][1536]
  u16* const f1ol  = f1oh + 6291456;
  u16* const avh   = (u16*)(P + 6291456);                // im2col planes [4096][1152]
  u16* const avl   = avh + 4718592;
  u16* const cwh   = (u16*)(P + 25165824);               // convw planes [384][1152]
  u16* const cwl   = cwh + 442368;
  u16* const xph   = (u16*)(P + 6291456);                // pooled planes [4096][512]
  u16* const xpl   = xph + 2097152;
  u16* const pih   = (u16*)(P + 14680064);               // proj_in_w planes [384][512]
  u16* const pil   = pih + 196608;
  float* const ypre = (float*)(P + 15466496);            // [4096][384] f32
  u16* const poh   = (u16*)(P + 6291456);                // proj_out_w planes [512][384]
  u16* const pol   = poh + 196608;
  float* const hp  = (float*)(P + 7077888);              // [4096][512] f32

  // ---- setup: pool + proj_in + LN_in ----
  pool_kernel<<<8192, 256, 0, stream>>>(x, xph, xpl);
  split_kernel<<<768, 256, 0, stream>>>(proj_in_w, pih, pil, 196608);
  mgemm<64, false, false><<<dim3(6, 32), 256, 0, stream>>>(
      xph, xpl, pih, pil, proj_in_b, nullptr, ypre, nullptr, nullptr, 384, 512);
  ln_kernel<false><<<4096, 128, 0, stream>>>(ypre, norm_in_g, norm_in_b, hbuf, nullptr, nullptr);

  for (int i = 0; i < 2; ++i) {
    // weight split+transpose for this layer
    tsplit_kernel<<<dim3(48, 12), 256, 0, stream>>>(wqkv + (size_t)i * 589824, wqh, wql, 384, 1536);
    tsplit_kernel<<<dim3(12, 16), 256, 0, stream>>>(wout + (size_t)i * 196608, woh, wol, 512, 384);
    tsplit_kernel<<<dim3(48, 12), 256, 0, stream>>>(ffw1 + (size_t)i * 589824, f1h_w, f1l_w, 384, 1536);
    tsplit_kernel<<<dim3(12, 48), 256, 0, stream>>>(ffw2 + (size_t)i * 589824, f2h_w, f2l_w, 1536, 384);

    ln_kernel<true><<<4096, 128, 0, stream>>>(hbuf, ln1_g + i * 384, ln1_b + i * 384,
                                              nullptr, ybh, ybl);
    // q proj -> qp
    mgemm<64, false, false><<<dim3(8, 32), 256, 0, stream>>>(
        ybh, ybl, wqh, wql, nullptr, nullptr, slotQ, nullptr, nullptr, 512, 384);
    nm_kernel<1, false><<<dim3(128, 4), 256, 0, stream>>>(slotQ, rf + (size_t)i * 4096,
        qpb, nullptr, nullptr, 131072L, 64L, 512L, 131072L, 16384L, 64L, 0L);
    // k proj -> kp
    mgemm<64, false, false><<<dim3(8, 32), 256, 0, stream>>>(
        ybh, ybl, wqh + 196608, wql + 196608, nullptr, nullptr, slotQ, nullptr, nullptr, 512, 384);
    nm_kernel<2, false><<<dim3(128, 4), 256, 0, stream>>>(slotQ, rf + (size_t)i * 4096,
        kpb, nullptr, nullptr, 131072L, 64L, 512L, 131072L, 16384L, 64L, 0L);
    // v proj
    mgemm<64, false, false><<<dim3(8, 32), 256, 0, stream>>>(
        ybh, ybl, wqh + 393216, wql + 393216, nullptr, nullptr, slotQ, nullptr, nullptr, 512, 384);
    // kv = kp^T @ v ; o = qp @ kv (split planes)
    kv_kernel<<<128, 256, 0, stream>>>(slotQ, kpb, kvb);
    nm_kernel<0, true><<<dim3(128, 4), 256, 0, stream>>>(qpb, kvb, nullptr, oh, ol,
        131072L, 16384L, 64L, 131072L, 64L, 512L, 4096L);
    // h += o @ wout + bout
    mgemm<64, false, false><<<dim3(6, 32), 256, 0, stream>>>(
        oh, ol, woh, wol, bout + i * 384, hbuf, hbuf, nullptr, nullptr, 384, 512);
    // FF
    ln_kernel<true><<<4096, 128, 0, stream>>>(hbuf, ln2_g + i * 384, ln2_b + i * 384,
                                              nullptr, ybh, ybl);
    mgemm<128, true, true><<<dim3(12, 32), 256, 0, stream>>>(
        ybh, ybl, f1h_w, f1l_w, ffb1 + i * 1536, nullptr, nullptr, f1oh, f1ol, 1536, 384);
    mgemm<64, false, false><<<dim3(6, 32), 256, 0, stream>>>(
        f1oh, f1ol, f2h_w, f2l_w, ffb2 + i * 384, hbuf, hbuf, nullptr, nullptr, 384, 1536);
  }

  // ---- local conv (im2col planes @ convw planes, residual into hbuf) ----
  convw_split_kernel<<<1728, 256, 0, stream>>>(local_w, cwh, cwl);
  gather_kernel<<<4608, 256, 0, stream>>>(hbuf, avh, avl);
  mgemm<64, false, false><<<dim3(6, 32), 256, 0, stream>>>(
      avh, avl, cwh, cwl, local_b, hbuf, hbuf, nullptr, nullptr, 384, 1152);

  // ---- LN_out + proj_out folded before interpolation ----
  ln_kernel<true><<<4096, 128, 0, stream>>>(hbuf, norm_out_g, norm_out_b, nullptr, ybh, ybl);
  split_kernel<<<768, 256, 0, stream>>>(proj_out_w, poh, pol, 196608);
  mgemm<64, false, false><<<dim3(8, 32), 256, 0, stream>>>(
      ybh, ybl, poh, pol, proj_out_b, nullptr, hp, nullptr, nullptr, 512, 384);

  // ---- interp + residual ----
  final_kernel<<<8192, 256, 0, stream>>>(hp, x, out);
}

// Round 3
// 784.781 us; speedup vs baseline: 1.7188x; 1.0876x over previous
//
#include <hip/hip_runtime.h>
#include <math.h>

typedef unsigned short u16;
typedef unsigned int u32;
typedef __bf16 bf16;
typedef __attribute__((ext_vector_type(8))) __bf16 bf16x8;
typedef __attribute__((ext_vector_type(4))) float f32x4;

#define NB 16
#define NC 512
#define NL 4096
#define ND 384
#define NW 256      // pooled length n
#define NIN 512     // inner
#define NFF 1536
#define NM (NB*NW)  // 4096 rows
#define ATT_SCALE 0.125f

__device__ __forceinline__ float gelu_f(float x) {
  return 0.5f * x * (1.f + erff(x * 0.70710678118654752f));
}

// ---- fp32 -> bf16 hi/lo split (RNE via bit math; lo = exact residual rounded)
__device__ __forceinline__ u16 bf_hi(float f) {
  u32 u = __float_as_uint(f);
  u32 r = u + 0x7FFFu + ((u >> 16) & 1u);
  return (u16)(r >> 16);
}
__device__ __forceinline__ float bf_f(u16 h) { return __uint_as_float((u32)h << 16); }
__device__ __forceinline__ void split_bf(float f, u16& h, u16& l) {
  h = bf_hi(f);
  l = bf_hi(f - bf_f(h));
}

// ---- pool: x[b][c][0:4096] -> mean over 16 -> split-bf16 planes xpT[(b*256+n)][c]
__global__ __launch_bounds__(256) void pool_kernel(const float* __restrict__ x,
                                                   u16* __restrict__ xh, u16* __restrict__ xl) {
  int blk = blockIdx.x;            // b*512 + c
  int b = blk >> 9, c = blk & 511;
  int t = threadIdx.x;             // window index n
  const float4* p = (const float4*)(x + (size_t)blk * NL) + t * 4;
  float s = 0.f;
#pragma unroll
  for (int i = 0; i < 4; ++i) {
    float4 v = p[i];
    s += v.x + v.y + v.z + v.w;
  }
  u16 hh, ll; split_bf(s * (1.f / 16.f), hh, ll);
  size_t off = ((size_t)b * NW + t) * NC + c;
  xh[off] = hh; xl[off] = ll;
}

// ---- elementwise split (weights already in [N][K] layout)
__global__ __launch_bounds__(256) void split_kernel(const float* __restrict__ src,
                                                    u16* __restrict__ dh, u16* __restrict__ dl, int n) {
  int i = blockIdx.x * 256 + threadIdx.x;
  if (i >= n) return;
  u16 h, l; split_bf(src[i], h, l);
  dh[i] = h; dl[i] = l;
}

// ---- transpose+split: src[R][C] f32 -> dst planes [C][R] bf16 (dst[c][r]=src[r][c])
__global__ __launch_bounds__(256) void tsplit_kernel(const float* __restrict__ src,
                                                     u16* __restrict__ dh, u16* __restrict__ dl,
                                                     int R, int C) {
  __shared__ float tile[32][33];
  const int tc = blockIdx.x * 32, tr = blockIdx.y * 32;
  const int lx = threadIdx.x & 31, ly = threadIdx.x >> 5;   // 32 x 8
#pragma unroll
  for (int p = 0; p < 4; ++p)
    tile[ly + p * 8][lx] = src[(size_t)(tr + ly + p * 8) * C + tc + lx];
  __syncthreads();
#pragma unroll
  for (int p = 0; p < 4; ++p) {
    const int c = tc + ly + p * 8;
    const float v = tile[lx][ly + p * 8];
    u16 h, l; split_bf(v, h, l);
    dh[(size_t)c * R + tr + lx] = h;
    dl[(size_t)c * R + tr + lx] = l;
  }
}

// ---- conv weight: BT[n=dout][k=j*384+dp] = local_w[dout][dp][j], split planes
__global__ __launch_bounds__(256) void convw_split_kernel(const float* __restrict__ lw,
                                                          u16* __restrict__ dh, u16* __restrict__ dl) {
  int idx = blockIdx.x * 256 + threadIdx.x;       // over 384*1152
  if (idx >= 384 * 1152) return;
  int n = idx / 1152, k = idx - n * 1152;
  int j = k / 384, dp = k - j * 384;
  u16 h, l; split_bf(lw[(size_t)n * 1152 + dp * 3 + j], h, l);
  dh[idx] = h; dl[idx] = l;
}

// ---- G = rf @ rf^T per layer (shared across heads). grid = 2 blocks.
__global__ __launch_bounds__(256) void g_kernel(const float* __restrict__ rf,
                                                float* __restrict__ G) {
  const int l = blockIdx.x;
  const float* rfp = rf + (size_t)l * 4096;
  __shared__ float rs[64][65];
  const int t = threadIdx.x;
#pragma unroll
  for (int i = 0; i < 16; ++i) {
    int idx = t + i * 256;
    rs[idx >> 6][idx & 63] = rfp[idx];
  }
  __syncthreads();
  const int d = t >> 2, e0 = (t & 3) * 16;
  float* gp = G + (size_t)l * 4096 + (size_t)d * 64 + e0;
#pragma unroll
  for (int j = 0; j < 16; ++j) {
    float s = 0.f;
    const int e = e0 + j;
#pragma unroll
    for (int m = 0; m < 64; ++m) s += rs[d][m] * rs[e][m];
    gp[j] = s;
  }
}

// ---- MFMA split-bf16 GEMM.  C[m][n] = f(A@B^T + bias) (+res)
// A planes: [M][K] bf16 hi/lo.  B planes: [N][K] bf16 hi/lo (pre-transposed weights).
// BM=128 fixed, BN in {64,128}. 256 threads = 4 waves (2x2), wave tile 64 x BN/2.
// LDS tiles [rows][32] bf16, XOR-swizzle idx^=((row&7)<<3) -> <=2-way bank conflicts (free).
// 3-product emulation: acc += Ah*Bh + Al*Bh + Ah*Bl  (drops Al*Bl ~ 2^-18 rel).
// TRANS epilogue (proj_out): writes hpT[(m>>8)*N + n][m&255] as float4 (coalesced final).
template<int BN, bool GELU, bool SPLITOUT, bool TRANS>
__global__ __launch_bounds__(256) void mgemm(
    const u16* __restrict__ Ah_g, const u16* __restrict__ Al_g,
    const u16* __restrict__ Bh_g, const u16* __restrict__ Bl_g,
    const float* __restrict__ bias, const float* res,
    float* C, u16* Ch, u16* Cl, int N, int K)
{
  constexpr int FN = BN / 32;
  constexpr int WN = BN / 2;
  __shared__ __align__(16) u16 Ah_s[128 * 32], Al_s[128 * 32];
  __shared__ __align__(16) u16 Bh_s[BN * 32],  Bl_s[BN * 32];

  const int t = threadIdx.x;
  const int bm = blockIdx.y * 128;
  const int bn = blockIdx.x * BN;

  // staging: 16B chunks; A has 512 chunks (2/thread), B has BN*4 chunks
  const int ra0 = t >> 2, ra1 = ra0 + 64;
  const int ca = (t & 3) * 8;
  const size_t ga0 = (size_t)(bm + ra0) * K + ca;
  const size_t ga1 = (size_t)(bm + ra1) * K + ca;
  const int wa0 = (ra0 * 32 + ca) ^ ((ra0 & 7) << 3);
  const int wa1 = (ra1 * 32 + ca) ^ ((ra1 & 7) << 3);
  const size_t gb0 = (size_t)(bn + ra0) * K + ca;
  const int wb0 = wa0;
  size_t gb1 = 0; int wb1 = 0;
  if constexpr (BN == 128) { gb1 = (size_t)(bn + ra1) * K + ca; wb1 = wa1; }

  // fragment offsets (A: row=lane&15, k=(lane>>4)*8+e ; B symmetric on [N][K])
  const int lane = t & 63;
  const int w = t >> 6, wm = w >> 1, wn = w & 1;
  const int lr = lane & 15;
  const int kb = (lane >> 4) << 3;
  int aoff[4], boff[FN];
#pragma unroll
  for (int i = 0; i < 4; ++i) {
    int r = wm * 64 + i * 16 + lr;
    aoff[i] = (r * 32 + kb) ^ ((r & 7) << 3);
  }
#pragma unroll
  for (int j = 0; j < FN; ++j) {
    int r = wn * WN + j * 16 + lr;
    boff[j] = (r * 32 + kb) ^ ((r & 7) << 3);
  }

  f32x4 acc[4][FN];
#pragma unroll
  for (int i = 0; i < 4; ++i)
#pragma unroll
    for (int j = 0; j < FN; ++j) acc[i][j] = (f32x4){0.f, 0.f, 0.f, 0.f};

  uint4 va0h, va0l, va1h, va1l, vb0h, vb0l, vb1h, vb1l;
  va0h = *(const uint4*)(Ah_g + ga0); va0l = *(const uint4*)(Al_g + ga0);
  va1h = *(const uint4*)(Ah_g + ga1); va1l = *(const uint4*)(Al_g + ga1);
  vb0h = *(const uint4*)(Bh_g + gb0); vb0l = *(const uint4*)(Bl_g + gb0);
  if constexpr (BN == 128) {
    vb1h = *(const uint4*)(Bh_g + gb1); vb1l = *(const uint4*)(Bl_g + gb1);
  }

  const int ksteps = K >> 5;
  for (int s = 0; s < ksteps; ++s) {
    __syncthreads();
    *(uint4*)&Ah_s[wa0] = va0h; *(uint4*)&Al_s[wa0] = va0l;
    *(uint4*)&Ah_s[wa1] = va1h; *(uint4*)&Al_s[wa1] = va1l;
    *(uint4*)&Bh_s[wb0] = vb0h; *(uint4*)&Bl_s[wb0] = vb0l;
    if constexpr (BN == 128) {
      *(uint4*)&Bh_s[wb1] = vb1h; *(uint4*)&Bl_s[wb1] = vb1l;
    }
    if (s + 1 < ksteps) {            // issue next-tile loads before MFMA block
      const int k0 = (s + 1) << 5;
      va0h = *(const uint4*)(Ah_g + ga0 + k0); va0l = *(const uint4*)(Al_g + ga0 + k0);
      va1h = *(const uint4*)(Ah_g + ga1 + k0); va1l = *(const uint4*)(Al_g + ga1 + k0);
      vb0h = *(const uint4*)(Bh_g + gb0 + k0); vb0l = *(const uint4*)(Bl_g + gb0 + k0);
      if constexpr (BN == 128) {
        vb1h = *(const uint4*)(Bh_g + gb1 + k0); vb1l = *(const uint4*)(Bl_g + gb1 + k0);
      }
    }
    __syncthreads();
    bf16x8 ah[4], al[4];
#pragma unroll
    for (int i = 0; i < 4; ++i) {
      ah[i] = *(const bf16x8*)&Ah_s[aoff[i]];
      al[i] = *(const bf16x8*)&Al_s[aoff[i]];
    }
#pragma unroll
    for (int j = 0; j < FN; ++j) {
      bf16x8 bh = *(const bf16x8*)&Bh_s[boff[j]];
      bf16x8 bl = *(const bf16x8*)&Bl_s[boff[j]];
#pragma unroll
      for (int i = 0; i < 4; ++i) {
        acc[i][j] = __builtin_amdgcn_mfma_f32_16x16x32_bf16(ah[i], bh, acc[i][j], 0, 0, 0);
        acc[i][j] = __builtin_amdgcn_mfma_f32_16x16x32_bf16(al[i], bh, acc[i][j], 0, 0, 0);
        acc[i][j] = __builtin_amdgcn_mfma_f32_16x16x32_bf16(ah[i], bl, acc[i][j], 0, 0, 0);
      }
    }
  }

  // epilogue: D col=lane&15, row=(lane>>4)*4+reg  [m89-verified layout]
  const int m0 = bm + wm * 64 + ((lane >> 4) << 2);
#pragma unroll
  for (int j = 0; j < FN; ++j) {
    const int n = bn + wn * WN + j * 16 + lr;
    const float bv = bias ? bias[n] : 0.f;
#pragma unroll
    for (int i = 0; i < 4; ++i) {
      if constexpr (TRANS) {
        const int mb = m0 + i * 16;        // multiple of 4, same b for all 4 r
        float4 o;
        o.x = acc[i][j][0] + bv; o.y = acc[i][j][1] + bv;
        o.z = acc[i][j][2] + bv; o.w = acc[i][j][3] + bv;
        *(float4*)(C + ((size_t)(mb >> 8) * N + n) * 256 + (mb & 255)) = o;
      } else {
#pragma unroll
        for (int r = 0; r < 4; ++r) {
          float v = acc[i][j][r] + bv;
          if constexpr (GELU) v = gelu_f(v);
          const size_t off = (size_t)(m0 + i * 16 + r) * N + n;
          if constexpr (SPLITOUT) {
            u16 hh, ll; split_bf(v, hh, ll);
            Ch[off] = hh; Cl[off] = ll;
          } else {
            if (res) v += res[off];   // res/C may alias (in-place residual) -> no restrict
            C[off] = v;
          }
        }
      }
    }
  }
}

// ---- layernorm over D=384; SPLIT=true writes bf16 hi/lo planes (GEMM A-operand)
template<bool SPLIT>
__global__ __launch_bounds__(128) void ln_kernel(const float* __restrict__ in,
                                                 const float* __restrict__ g,
                                                 const float* __restrict__ bb,
                                                 float* __restrict__ out,
                                                 u16* __restrict__ oh, u16* __restrict__ ol)
{
  int row = blockIdx.x, t = threadIdx.x;
  const float* p = in + (size_t)row * ND;
  float v0 = p[t], v1 = p[t + 128], v2 = p[t + 256];
  float s1 = v0 + v1 + v2;
  float s2 = v0 * v0 + v1 * v1 + v2 * v2;
#pragma unroll
  for (int off = 32; off > 0; off >>= 1) {
    s1 += __shfl_down(s1, off);
    s2 += __shfl_down(s2, off);
  }
  __shared__ float sh[4];
  if ((t & 63) == 0) { sh[(t >> 6) * 2] = s1; sh[(t >> 6) * 2 + 1] = s2; }
  __syncthreads();
  float t1 = sh[0] + sh[2], t2 = sh[1] + sh[3];
  float mean = t1 * (1.f / ND);
  float var = t2 * (1.f / ND) - mean * mean;
  float rs = rsqrtf(var + 1e-5f);
  float o0 = (v0 - mean) * rs * g[t]       + bb[t];
  float o1 = (v1 - mean) * rs * g[t + 128] + bb[t + 128];
  float o2 = (v2 - mean) * rs * g[t + 256] + bb[t + 256];
  if constexpr (SPLIT) {
    size_t rb = (size_t)row * ND;
    u16 hh, ll;
    split_bf(o0, hh, ll); oh[rb + t]       = hh; ol[rb + t]       = ll;
    split_bf(o1, hh, ll); oh[rb + t + 128] = hh; ol[rb + t + 128] = ll;
    split_bf(o2, hh, ll); oh[rb + t + 256] = hh; ol[rb + t + 256] = ll;
  } else {
    float* q = out + (size_t)row * ND;
    q[t] = o0; q[t + 128] = o1; q[t + 256] = o2;
  }
}

// ---- per-head [n x 64] = f(in[n][0:64]) @ mat[64][64]
// MODE: 0 plain, 1 relu*SCALE, 2 relu.  SPLIT: write bf16 hi/lo planes.
template<int MODE, bool SPLIT>
__global__ __launch_bounds__(256) void nm_kernel(
    const float* __restrict__ in, const float* __restrict__ mat,
    float* __restrict__ out, u16* __restrict__ oh, u16* __restrict__ ol,
    long sb_in, long sh_in, long sn_in,
    long sb_out, long sh_out, long sn_out,
    long mat_sbh)
{
  int bh = blockIdx.x;   // 0..127
  int nq = blockIdx.y;   // 0..3 (64-row slab)
  int b = bh >> 3, h = bh & 7;
  int t = threadIdx.x;
  __shared__ float ms[4096];      // mat [contract][out]
  __shared__ float xs[16][68];    // staged input rows (padded)
  const float* mp = mat + (size_t)bh * mat_sbh;
#pragma unroll
  for (int i = 0; i < 4; ++i) {
    int idx = t + 256 * i;
    ((float4*)ms)[idx] = ((const float4*)mp)[idx];
  }
  const float* ip = in + (size_t)b * sb_in + (size_t)h * sh_in;
  float* op = nullptr; u16* ohp = nullptr; u16* olp = nullptr;
  if constexpr (SPLIT) {
    ohp = oh + (size_t)b * sb_out + (size_t)h * sh_out;
    olp = ol + (size_t)b * sb_out + (size_t)h * sh_out;
  } else {
    op = out + (size_t)b * sb_out + (size_t)h * sh_out;
  }
  int nr = t >> 4, q4 = (t & 15) * 4;
  for (int p = 0; p < 4; ++p) {
    int nbase = nq * 64 + p * 16 + nr;
    __syncthreads();   // mat staged (p==0) / previous pass's readers done
    float4 v = *(const float4*)(ip + (size_t)nbase * sn_in + q4);
    if (MODE == 1) {
      v.x = fmaxf(v.x, 0.f) * ATT_SCALE; v.y = fmaxf(v.y, 0.f) * ATT_SCALE;
      v.z = fmaxf(v.z, 0.f) * ATT_SCALE; v.w = fmaxf(v.w, 0.f) * ATT_SCALE;
    } else if (MODE == 2) {
      v.x = fmaxf(v.x, 0.f); v.y = fmaxf(v.y, 0.f);
      v.z = fmaxf(v.z, 0.f); v.w = fmaxf(v.w, 0.f);
    }
    *(float4*)&xs[nr][q4] = v;
    __syncthreads();
    float fx = 0.f, fy = 0.f, fz = 0.f, fw = 0.f;
#pragma unroll
    for (int d = 0; d < 64; ++d) {
      float a = xs[nr][d];
      const float4 mm = *(const float4*)&ms[d * 64 + q4];
      fx += a * mm.x; fy += a * mm.y; fz += a * mm.z; fw += a * mm.w;
    }
    if constexpr (SPLIT) {
      u16 h0, l0, h1, l1, h2, l2, h3, l3;
      split_bf(fx, h0, l0); split_bf(fy, h1, l1);
      split_bf(fz, h2, l2); split_bf(fw, h3, l3);
      ushort4 hv; hv.x = h0; hv.y = h1; hv.z = h2; hv.w = h3;
      ushort4 lv; lv.x = l0; lv.y = l1; lv.z = l2; lv.w = l3;
      *(ushort4*)(ohp + (size_t)nbase * sn_out + q4) = hv;
      *(ushort4*)(olp + (size_t)nbase * sn_out + q4) = lv;
    } else {
      float4 o; o.x = fx; o.y = fy; o.z = fz; o.w = fw;
      *(float4*)(op + (size_t)nbase * sn_out + q4) = o;
    }
  }
}

// ---- fused kv+G: per bh, KV = relu(k)^T @ v  (k,v from merged qkv buffer),
// then M2 = G @ KV  (G = rf rf^T, per layer). One dispatch replaces kp-nm + kv.
__global__ __launch_bounds__(256) void kvg_kernel(const float* __restrict__ qkvb,
                                                  const float* __restrict__ Gl,
                                                  float* __restrict__ m2)
{
  int bh = blockIdx.x;
  int b = bh >> 3, h = bh & 7;
  int t = threadIdx.x;
  __shared__ float s1[64][68];     // loop: relu(k) tile rows 0..15 ; after: KV [64][64]
  __shared__ float s2[64][68];     // loop: v tile rows 0..15       ; after: G  [64][64]
  int m = t >> 2, dq = t & 3;
  int nr = t >> 4, c4 = (t & 15) * 4;
  const float* kbase = qkvb + (size_t)b * NW * NFF + 512 + h * 64;
  const float* vbase = qkvb + (size_t)b * NW * NFF + 1024 + h * 64;
  float4 a0 = {0,0,0,0}, a1 = {0,0,0,0}, a2 = {0,0,0,0}, a3 = {0,0,0,0};
  for (int p = 0; p < 16; ++p) {
    __syncthreads();
    float4 kv4 = *(const float4*)(kbase + (size_t)(p * 16 + nr) * NFF + c4);
    kv4.x = fmaxf(kv4.x, 0.f); kv4.y = fmaxf(kv4.y, 0.f);
    kv4.z = fmaxf(kv4.z, 0.f); kv4.w = fmaxf(kv4.w, 0.f);
    *(float4*)&s1[nr][c4] = kv4;
    *(float4*)&s2[nr][c4] = *(const float4*)(vbase + (size_t)(p * 16 + nr) * NFF + c4);
    __syncthreads();
#pragma unroll
    for (int nn = 0; nn < 16; ++nn) {
      float a = s1[nn][m];
      const float4 v0 = *(const float4*)&s2[nn][dq * 16 + 0];
      const float4 v1 = *(const float4*)&s2[nn][dq * 16 + 4];
      const float4 v2 = *(const float4*)&s2[nn][dq * 16 + 8];
      const float4 v3 = *(const float4*)&s2[nn][dq * 16 + 12];
      a0.x += a * v0.x; a0.y += a * v0.y; a0.z += a * v0.z; a0.w += a * v0.w;
      a1.x += a * v1.x; a1.y += a * v1.y; a1.z += a * v1.z; a1.w += a * v1.w;
      a2.x += a * v2.x; a2.y += a * v2.y; a2.z += a * v2.z; a2.w += a * v2.w;
      a3.x += a * v3.x; a3.y += a * v3.y; a3.z += a * v3.z; a3.w += a * v3.w;
    }
  }
  // KV -> s1 (full 64x64), G -> s2
  __syncthreads();
  *(float4*)&s1[m][dq * 16 + 0]  = a0;
  *(float4*)&s1[m][dq * 16 + 4]  = a1;
  *(float4*)&s1[m][dq * 16 + 8]  = a2;
  *(float4*)&s1[m][dq * 16 + 12] = a3;
#pragma unroll
  for (int i = 0; i < 16; ++i) {
    int idx = t + i * 256;
    s2[idx >> 6][idx & 63] = Gl[idx];
  }
  __syncthreads();
  // M2[m][d] = sum_p G[m][p] * KV[p][d]
  float4 o0 = {0,0,0,0}, o1 = {0,0,0,0}, o2 = {0,0,0,0}, o3 = {0,0,0,0};
#pragma unroll 4
  for (int p = 0; p < 64; ++p) {
    float g = s2[m][p];
    const float4 v0 = *(const float4*)&s1[p][dq * 16 + 0];
    const float4 v1 = *(const float4*)&s1[p][dq * 16 + 4];
    const float4 v2 = *(const float4*)&s1[p][dq * 16 + 8];
    const float4 v3 = *(const float4*)&s1[p][dq * 16 + 12];
    o0.x += g * v0.x; o0.y += g * v0.y; o0.z += g * v0.z; o0.w += g * v0.w;
    o1.x += g * v1.x; o1.y += g * v1.y; o1.z += g * v1.z; o1.w += g * v1.w;
    o2.x += g * v2.x; o2.y += g * v2.y; o2.z += g * v2.z; o2.w += g * v2.w;
    o3.x += g * v3.x; o3.y += g * v3.y; o3.z += g * v3.z; o3.w += g * v3.w;
  }
  float* op = m2 + (size_t)bh * 4096 + (size_t)m * 64 + dq * 16;
  *(float4*)(op + 0) = o0; *(float4*)(op + 4) = o1;
  *(float4*)(op + 8) = o2; *(float4*)(op + 12) = o3;
}

// ---- im2col for conv1d k=3 pad=1 -> split planes Acv[4096][1152]
__global__ __launch_bounds__(256) void gather_kernel(const float* __restrict__ h,
                                                     u16* __restrict__ dh, u16* __restrict__ dl)
{
  int idx = blockIdx.x * 256 + threadIdx.x;   // float4 units over [4096][1152]
  if (idx >= 4096 * 288) return;
  int c4 = idx % 288;
  int m = idx / 288;
  int col = c4 * 4;
  int j = col / 384;
  int d = col - j * 384;
  int n = m & 255;
  int nn = n + j - 1;
  float4 v = {0, 0, 0, 0};
  if (nn >= 0 && nn < 256) v = *(const float4*)(h + (size_t)(m + j - 1) * ND + d);
  u16 h0, l0, h1, l1, h2, l2, h3, l3;
  split_bf(v.x, h0, l0); split_bf(v.y, h1, l1);
  split_bf(v.z, h2, l2); split_bf(v.w, h3, l3);
  ushort4 hv; hv.x = h0; hv.y = h1; hv.z = h2; hv.w = h3;
  ushort4 lv; lv.x = l0; lv.y = l1; lv.z = l2; lv.w = l3;
  size_t off = (size_t)m * 1152 + col;
  *(ushort4*)(dh + off) = hv;
  *(ushort4*)(dl + off) = lv;
}

// ---- final: one block per (b,c) row; hpT[b][c][0:256] is CONTIGUOUS (TRANS
// epilogue) -> fully coalesced 1-float/lane stage. Each thread owns an aligned
// 16-sample group with compile-time interp weights; edge clamp matches ref.
__global__ __launch_bounds__(256) void final_kernel(const float* __restrict__ hpT,
                                                    const float* __restrict__ x,
                                                    float* __restrict__ out)
{
  __shared__ float ls[256];
  const int blk = blockIdx.x;      // b*512 + c
  const int t = threadIdx.x;       // group index g = pooled position n
  ls[t] = hpT[(size_t)blk * NW + t];
  __syncthreads();
  const float h0 = ls[t == 0 ? 0 : t - 1];
  const float h1 = ls[t];
  const float h2 = ls[t == 255 ? 255 : t + 1];
  const float d01 = h1 - h0, d12 = h2 - h1;
  float o[16];
#pragma unroll
  for (int r = 0; r < 8; ++r) o[r]     = h0 + d01 * ((r + 8.5f) * 0.0625f);
#pragma unroll
  for (int r = 0; r < 8; ++r) o[r + 8] = h1 + d12 * ((r + 0.5f) * 0.0625f);
  const float4* xp = (const float4*)(x + (size_t)blk * NL + t * 16);
  float4* op = (float4*)(out + (size_t)blk * NL + t * 16);
#pragma unroll
  for (int j = 0; j < 4; ++j) {
    float4 xv = xp[j];
    float4 res;
    res.x = o[j * 4 + 0] + xv.x;
    res.y = o[j * 4 + 1] + xv.y;
    res.z = o[j * 4 + 2] + xv.z;
    res.w = o[j * 4 + 3] + xv.w;
    op[j] = res;
  }
}

extern "C" void kernel_launch(void* const* d_in, const int* in_sizes, int n_in,
                              void* d_out, int out_size, void* d_ws, size_t ws_size,
                              hipStream_t stream)
{
  const float* x          = (const float*)d_in[0];
  const float* proj_in_w  = (const float*)d_in[1];
  const float* proj_in_b  = (const float*)d_in[2];
  const float* norm_in_g  = (const float*)d_in[3];
  const float* norm_in_b  = (const float*)d_in[4];
  const float* ln1_g      = (const float*)d_in[5];
  const float* ln1_b      = (const float*)d_in[6];
  const float* wqkv       = (const float*)d_in[7];
  const float* rf         = (const float*)d_in[8];
  const float* wout       = (const float*)d_in[9];
  const float* bout       = (const float*)d_in[10];
  const float* ln2_g      = (const float*)d_in[11];
  const float* ln2_b      = (const float*)d_in[12];
  const float* ffw1       = (const float*)d_in[13];
  const float* ffb1       = (const float*)d_in[14];
  const float* ffw2       = (const float*)d_in[15];
  const float* ffb2       = (const float*)d_in[16];
  const float* local_w    = (const float*)d_in[17];
  const float* local_b    = (const float*)d_in[18];
  const float* norm_out_g = (const float*)d_in[19];
  const float* norm_out_b = (const float*)d_in[20];
  const float* proj_out_w = (const float*)d_in[21];
  const float* proj_out_b = (const float*)d_in[22];
  float* out = (float*)d_out;

  // ---- workspace layout (48 MiB) ----
  char* const base = (char*)d_ws;
  float* const hbuf = (float*)base;                      // [4096][384] f32 (6,291,456 B)
  // per-layer weight slots (split-bf16, transposed to [N][K]); re-split each layer
  u16* const wqh   = (u16*)(base + 6291456);             // wqkvT [1536][384]
  u16* const wql   = wqh + 589824;
  u16* const woh   = wql + 589824;                       // woutT [384][512]
  u16* const wol   = woh + 196608;
  u16* const f1h_w = wol + 196608;                       // ffw1T [1536][384]
  u16* const f1l_w = f1h_w + 589824;
  u16* const f2h_w = f1l_w + 589824;                     // ffw2T [384][1536]
  u16* const f2l_w = f2h_w + 589824;                     // ends base+14,155,776
  float* const Gbuf = (float*)(base + 14155776);         // [2][64][64] f32 (131,072 B)
  char* const P = base + 14286848;                       // phase pool (36,044,800 B)

  // setup phase
  u16* const xph  = (u16*)P;                             // [4096][512] planes
  u16* const xpl  = xph + 2097152;
  u16* const pih  = (u16*)(P + 8388608);                 // proj_in_w planes [384][512]
  u16* const pil  = pih + 196608;
  float* const ypre = (float*)(P + 9175040);             // [4096][384] f32

  // attention phase
  float* const qkvb = (float*)P;                         // [4096][1536] f32 (25,165,824 B)
  u16* const ybh1 = (u16*)(P + 25165824);                // ln1 planes [4096][384]
  u16* const ybl1 = ybh1 + 1572864;
  u16* const oh   = (u16*)(P + 25165824);                // attn-o planes [4096][512] (overlay ybh1)
  u16* const ol   = oh + 2097152;                        // ends P+33,554,432
  float* const m2b = (float*)(P + 33554432);             // [128][64][64] f32 (2,097,152 B)

  // ff phase
  u16* const ybh2 = (u16*)P;                             // ln2 planes
  u16* const ybl2 = ybh2 + 1572864;
  u16* const f1oh = (u16*)(P + 6291456);                 // ff1-out planes [4096][1536]
  u16* const f1ol = f1oh + 6291456;                      // ends P+31,457,280

  // conv phase
  u16* const avh  = (u16*)P;                             // im2col planes [4096][1152]
  u16* const avl  = avh + 4718592;
  u16* const cwh  = (u16*)(P + 18874368);                // convw planes [384][1152]
  u16* const cwl  = cwh + 442368;

  // out phase
  u16* const ybh3 = (u16*)P;                             // ln_out planes
  u16* const ybl3 = ybh3 + 1572864;
  u16* const poh  = (u16*)(P + 6291456);                 // proj_out_w planes [512][384]
  u16* const pol  = poh + 196608;
  float* const hpT = (float*)(P + 7077888);              // [16][512][256] f32 (8,388,608 B)

  // ---- setup: G precompute + pool + proj_in + LN_in ----
  g_kernel<<<2, 256, 0, stream>>>(rf, Gbuf);
  pool_kernel<<<8192, 256, 0, stream>>>(x, xph, xpl);
  split_kernel<<<768, 256, 0, stream>>>(proj_in_w, pih, pil, 196608);
  mgemm<64, false, false, false><<<dim3(6, 32), 256, 0, stream>>>(
      xph, xpl, pih, pil, proj_in_b, nullptr, ypre, nullptr, nullptr, 384, 512);
  ln_kernel<false><<<4096, 128, 0, stream>>>(ypre, norm_in_g, norm_in_b, hbuf, nullptr, nullptr);

  const long sbQ = 256L * NFF;    // qkv row-block stride per b

  for (int i = 0; i < 2; ++i) {
    // weight split+transpose for this layer
    tsplit_kernel<<<dim3(48, 12), 256, 0, stream>>>(wqkv + (size_t)i * 589824, wqh, wql, 384, 1536);
    tsplit_kernel<<<dim3(12, 16), 256, 0, stream>>>(wout + (size_t)i * 196608, woh, wol, 512, 384);
    tsplit_kernel<<<dim3(48, 12), 256, 0, stream>>>(ffw1 + (size_t)i * 589824, f1h_w, f1l_w, 384, 1536);
    tsplit_kernel<<<dim3(12, 48), 256, 0, stream>>>(ffw2 + (size_t)i * 589824, f2h_w, f2l_w, 1536, 384);

    ln_kernel<true><<<4096, 128, 0, stream>>>(hbuf, ln1_g + i * 384, ln1_b + i * 384,
                                              nullptr, ybh1, ybl1);
    // merged qkv projection: [4096][1536] f32
    mgemm<64, false, false, false><<<dim3(24, 32), 256, 0, stream>>>(
        ybh1, ybl1, wqh, wql, nullptr, nullptr, qkvb, nullptr, nullptr, NFF, 384);
    // KV = relu(k)^T @ v, then M2 = G @ KV (rf-fold)
    kvg_kernel<<<128, 256, 0, stream>>>(qkvb, Gbuf + (size_t)i * 4096, m2b);
    // o = relu(q)*scale @ M2 -> split planes
    nm_kernel<1, true><<<dim3(128, 4), 256, 0, stream>>>(qkvb, m2b, nullptr, oh, ol,
        sbQ, 64L, (long)NFF, 131072L, 64L, 512L, 4096L);
    // h += o @ wout + bout
    mgemm<64, false, false, false><<<dim3(6, 32), 256, 0, stream>>>(
        oh, ol, woh, wol, bout + i * 384, hbuf, hbuf, nullptr, nullptr, 384, 512);
    // FF
    ln_kernel<true><<<4096, 128, 0, stream>>>(hbuf, ln2_g + i * 384, ln2_b + i * 384,
                                              nullptr, ybh2, ybl2);
    mgemm<128, true, true, false><<<dim3(12, 32), 256, 0, stream>>>(
        ybh2, ybl2, f1h_w, f1l_w, ffb1 + i * 1536, nullptr, nullptr, f1oh, f1ol, 1536, 384);
    mgemm<64, false, false, false><<<dim3(6, 32), 256, 0, stream>>>(
        f1oh, f1ol, f2h_w, f2l_w, ffb2 + i * 384, hbuf, hbuf, nullptr, nullptr, 384, 1536);
  }

  // ---- local conv (im2col planes @ convw planes, residual into hbuf) ----
  convw_split_kernel<<<1728, 256, 0, stream>>>(local_w, cwh, cwl);
  gather_kernel<<<4608, 256, 0, stream>>>(hbuf, avh, avl);
  mgemm<64, false, false, false><<<dim3(6, 32), 256, 0, stream>>>(
      avh, avl, cwh, cwl, local_b, hbuf, hbuf, nullptr, nullptr, 384, 1152);

  // ---- LN_out + proj_out (transposed epilogue) ----
  ln_kernel<true><<<4096, 128, 0, stream>>>(hbuf, norm_out_g, norm_out_b, nullptr, ybh3, ybl3);
  split_kernel<<<768, 256, 0, stream>>>(proj_out_w, poh, pol, 196608);
  mgemm<64, false, false, true><<<dim3(8, 32), 256, 0, stream>>>(
      ybh3, ybl3, poh, pol, proj_out_b, nullptr, hpT, nullptr, nullptr, 512, 384);

  // ---- interp + residual ----
  final_kernel<<<8192, 256, 0, stream>>>(hpT, x, out);
}